// Round 6
// baseline (13358.557 us; speedup 1.0000x reference)
//
#include <hip/hip_runtime.h>
#include <math.h>

// ---------------------------------------------------------------------------
// MDN-RNN round 6: persistent kernel, cluster publish/poll (as r5), but the
// MDN head is fully off the LSTM critical path:
//  - hlds double-buffered: L1 reads PREVIOUS step's staged h in phase A.
//  - Phase A (concurrent, disjoint threads): L2(0-99), L3+FIN(100-269),
//    pollers(270-285), L1(312-511, k-split 2). Deep unroll + 2 chains on all
//    head loops -> latency-hiding on L2-resident weights.
//  - Phase D: pure LSTM on ALL 512 threads (ul16 x kq8 x bq4).
//  - Lags: L1@s:h_{s-1} | L2: h_{s-2} | L3: h_{s-3} | FIN: h_{s-4} -> t=s-5.
//    Loop s=0..1027.  x loads nontemporal (protect L2-resident head weights).
// ---------------------------------------------------------------------------

#define NOUT  1023
#define KK    5

// ws layout (floats)
#define OFF_H    0            // 2 x 65536 ping-pong h[par][u][b]
#define OFF_FLG  131072       // 256 uint publish flags [g16][ut16]
#define OFF_WHH  131136       // float4[65536]: Wg_hh[k][u][4g]
#define OFF_WIH  393280       // float4[8960] : Wg_ih[j][u][4g]
#define OFF_BG   429120       // float4[256]  : bias[u][4g]
#define OFF_W1T  430144       // [256k][128ch]
#define OFF_W2T  462912       // [100k][128ch]
#define OFF_W3T  475712       // [100k][192ch]

#define MEANBASE (256 * NOUT * KK)
#define VARBASE  (MEANBASE + 256 * NOUT * KK * 32)

__device__ __forceinline__ float sigf(float x) { return 1.0f / (1.0f + expf(-x)); }

// --------------------------- one-time weight pack ---------------------------
__global__ __launch_bounds__(256) void prep_pack(
    const float* __restrict__ W_ih, const float* __restrict__ W_hh,
    const float* __restrict__ b_ih, const float* __restrict__ b_hh,
    const float* __restrict__ W1,   const float* __restrict__ W2,
    const float* __restrict__ W3,   float* __restrict__ ws)
{
    const int idx = blockIdx.x * 256 + threadIdx.x;
    if (idx < 65536) {
        int k = idx >> 8, u = idx & 255;
        float4 v;
        v.x = W_hh[(0 * 256 + u) * 256 + k];
        v.y = W_hh[(1 * 256 + u) * 256 + k];
        v.z = W_hh[(2 * 256 + u) * 256 + k];
        v.w = W_hh[(3 * 256 + u) * 256 + k];
        ((float4*)(ws + OFF_WHH))[idx] = v;
    } else if (idx < 74496) {
        int r = idx - 65536;
        int j = r >> 8, u = r & 255;
        float4 v;
        v.x = W_ih[(0 * 256 + u) * 35 + j];
        v.y = W_ih[(1 * 256 + u) * 35 + j];
        v.z = W_ih[(2 * 256 + u) * 35 + j];
        v.w = W_ih[(3 * 256 + u) * 35 + j];
        ((float4*)(ws + OFF_WIH))[r] = v;
    } else if (idx < 74752) {
        int u = idx - 74496;
        float4 v;
        v.x = b_ih[0 * 256 + u] + b_hh[0 * 256 + u];
        v.y = b_ih[1 * 256 + u] + b_hh[1 * 256 + u];
        v.z = b_ih[2 * 256 + u] + b_hh[2 * 256 + u];
        v.w = b_ih[3 * 256 + u] + b_hh[3 * 256 + u];
        ((float4*)(ws + OFF_BG))[u] = v;
    } else if (idx < 107520) {
        int r = idx - 74752;
        int k = r >> 7, c = r & 127;
        if (c < 100) ws[OFF_W1T + k * 128 + c] = W1[c * 256 + k];
    } else if (idx < 120320) {
        int r = idx - 107520;
        int k = r >> 7, c = r & 127;
        if (c < 100) ws[OFF_W2T + k * 128 + c] = W2[c * 100 + k];
    } else if (idx < 139520) {
        int r = idx - 120320;
        int k = r / 192, c = r - k * 192;
        if (c < 170) ws[OFF_W3T + k * 192 + c] = W3[c * 100 + k];
    }
}

// ------------------------------ persistent kernel ---------------------------
__global__ __launch_bounds__(512, 1) void mdn_rnn_persist(
    const float* __restrict__ x,
    const float* __restrict__ b1, const float* __restrict__ b2,
    const float* __restrict__ b3,
    float* __restrict__ ws, float* __restrict__ out)
{
    __shared__ float4 wlds4[4360];      // W_hh slice: k*17 + ul + (k>>5)
    __shared__ float4 xlds4[595];       // W_ih slice: j*17 + ul
    __shared__ float4 bg[16];
    __shared__ float  hlds[2][4096];    // staged h double buffer (swizzled)
    __shared__ float  xst[2][700];      // x ping-pong [j][20]
    __shared__ float4 p4[2176];         // LSTM partials (kq*16+ul)*17 + col
    __shared__ float  ph1[2][104];      // L1 k-half partials
    __shared__ float  hid1L[2][104];
    __shared__ float  hid2L[2][104];
    __shared__ float  oL[2][176];
    __shared__ float  cvbuf[80];        // coeff/var staging [8t][10]

    const int tid = threadIdx.x;
    const int wg  = blockIdx.x;
    const int ut  = wg >> 4;
    const int g   = wg & 15;
    const int u0  = ut * 16;
    const int b0  = g * 16;
    const int bhead = b0 + ut;

    // D mapping (all 512 threads)
    const int ul = tid & 15;
    const int kq = (tid >> 4) & 7;
    const int bq = tid >> 7;                 // 0..3
    const int q0 = (bq + kq) & 3;
    const int joff = (kq < 3) ? kq * 5 : 15 + (kq - 3) * 4;
    const int jcnt = (kq < 3) ? 5 : 4;
    // stage mapping
    const int su = tid >> 1, shf = tid & 1;
    // x prefetch mapping (tid < 280)
    const int e0 = tid * 2,  pb0 = e0 / 35, pj0 = e0 - pb0 * 35;
    const int e1 = e0 + 1,   pb1 = e1 / 35, pj1 = e1 - pb1 * 35;
    // L1 swizzle constant for column ut
    const int c2 = ut >> 2, c3 = ut & 3;

    const float4* Wg4 = (const float4*)(ws + OFF_WHH);
    const float4* Wx4 = (const float4*)(ws + OFF_WIH);
    const float4* Bg4 = (const float4*)(ws + OFF_BG);
    const float*  W1T = ws + OFF_W1T;
    const float*  W2T = ws + OFF_W2T;
    const float*  W3T = ws + OFF_W3T;
    float* hbuf = ws + OFF_H;
    unsigned* flags = (unsigned*)(ws + OFF_FLG);

    // ---- one-time staging ----
    for (int i = tid; i < 4096; i += 512) {
        int k = i >> 4, uu = i & 15;
        wlds4[k * 17 + uu + (k >> 5)] = Wg4[k * 256 + u0 + uu];
    }
    for (int i = tid; i < 560; i += 512) {
        int j = i >> 4, uu = i & 15;
        xlds4[j * 17 + uu] = Wx4[j * 256 + u0 + uu];
    }
    if (tid < 16) bg[tid] = Bg4[u0 + tid];
    if (tid < 280) {
        xst[0][pj0 * 20 + pb0] = x[(size_t)(b0 + pb0) * 35840 + pj0];
        xst[0][pj1 * 20 + pb1] = x[(size_t)(b0 + pb1) * 35840 + pj1];
    }
    __syncthreads();

    float c_reg = 0.0f;

    for (int s = 0; s < 1028; ++s) {
        const int parC = s & 1;
        const int parN = parC ^ 1;

        // ================= A: head roles + pollers (concurrent) ============
        float xpf0 = 0.f, xpf1 = 0.f;
        const bool dopf = (s < 1022) && (tid < 280);
        if (dopf) {
            const float* xp = x + (size_t)(s + 1) * 35;
            xpf0 = __builtin_nontemporal_load(xp + (size_t)(b0 + pb0) * 35840 + pj0);
            xpf1 = __builtin_nontemporal_load(xp + (size_t)(b0 + pb1) * 35840 + pj1);
        }
        if (tid < 100) {                                    // L2: hid2(h_{s-2})
            if (s >= 3 && s <= 1025) {
                float a0 = 0.f, a1 = 0.f;
                #pragma unroll 25
                for (int k = 0; k < 50; ++k) {
                    a0 = fmaf(W2T[k * 128 + tid],        hid1L[parN][k],      a0);
                    a1 = fmaf(W2T[(k + 50) * 128 + tid], hid1L[parN][k + 50], a1);
                }
                hid2L[parC][tid] = fmaxf(a0 + a1 + b2[tid], 0.f);
            }
        } else if (tid < 270) {                             // L3 + FIN
            const int ch = tid - 100;
            if (s >= 4 && s <= 1026) {                      // o(h_{s-3})
                float a0 = 0.f, a1 = 0.f;
                #pragma unroll 25
                for (int k = 0; k < 50; ++k) {
                    a0 = fmaf(W3T[k * 192 + ch],        hid2L[parN][k],      a0);
                    a1 = fmaf(W3T[(k + 50) * 192 + ch], hid2L[parN][k + 50], a1);
                }
                oL[parC][ch] = a0 + a1 + b3[ch];
            }
            if (s >= 5) {                                   // FIN: t = s-5
                const int t = s - 5;
                float m5 = oL[parN][0];
                #pragma unroll
                for (int k = 1; k < KK; ++k) m5 = fmaxf(m5, oL[parN][k]);
                float den = 0.f;
                #pragma unroll
                for (int k = 0; k < KK; ++k) den += expf(oL[parN][k] - m5);
                float v = oL[parN][ch];
                if (ch < KK) {
                    cvbuf[(t & 7) * 10 + ch] = expf(v - m5) / den;
                } else if (ch < 2 * KK) {
                    cvbuf[(t & 7) * 10 + ch] = expf(v);
                } else {
                    out[MEANBASE + ((size_t)bhead * NOUT + t) * 160 + (ch - 10)] = v;
                }
            }
        } else if (tid < 286) {                             // pollers
            if (s >= 1 && s <= 1023) {
                const unsigned tgt = (unsigned)s;
                while (__hip_atomic_load(&flags[g * 16 + (tid - 270)],
                                         __ATOMIC_RELAXED,
                                         __HIP_MEMORY_SCOPE_AGENT) < tgt)
                    __builtin_amdgcn_s_sleep(1);
            }
        } else if (tid >= 312) {                            // L1: hid1(h_{s-1})
            if (s >= 2 && s <= 1024) {
                const int r  = tid - 312;                   // 0..199
                const int ch = (r < 100) ? r : r - 100;
                const int kh = (r < 100) ? 0 : 1;
                const int kb = kh * 128;
                const float* hp = hlds[parN];
                float a0 = 0.f, a1 = 0.f;
                #pragma unroll 16
                for (int i = 0; i < 64; ++i) {
                    const int k0 = kb + i, k1 = kb + 64 + i;
                    float h0 = hp[k0 * 16 + (((c2 + (k0 >> 5)) & 3) * 4) + c3];
                    float h1 = hp[k1 * 16 + (((c2 + (k1 >> 5)) & 3) * 4) + c3];
                    a0 = fmaf(W1T[k0 * 128 + ch], h0, a0);
                    a1 = fmaf(W1T[k1 * 128 + ch], h1, a1);
                }
                ph1[kh][ch] = a0 + a1;
            }
        }
        __syncthreads();  // sync1: poll complete, head state advanced

        // ================= C: stage h_s global -> hlds[parC] ===============
        if (s <= 1023) {
            const unsigned long long* src = (const unsigned long long*)
                (hbuf + parC * 65536 + su * 256 + b0 + shf * 8);
            unsigned long long v[4];
            #pragma unroll
            for (int i = 0; i < 4; ++i)
                v[i] = __hip_atomic_load(src + i, __ATOMIC_RELAXED,
                                         __HIP_MEMORY_SCOPE_AGENT);
            const int qb = su >> 5;
            #pragma unroll
            for (int i = 0; i < 4; ++i) {
                const int c = shf * 8 + i * 2;
                const int q = (((c >> 2) + qb) & 3);
                float2 f2;
                f2.x = __uint_as_float((unsigned)v[i]);
                f2.y = __uint_as_float((unsigned)(v[i] >> 32));
                *(float2*)&hlds[parC][su * 16 + q * 4 + (c & 3)] = f2;
            }
        }
        __syncthreads();  // sync2

        // ================= D: LSTM partials, ALL 512 threads ===============
        if (s <= 1022) {
            float4 acc0 = make_float4(0.f, 0.f, 0.f, 0.f);
            float4 acc1 = acc0, acc2 = acc0, acc3 = acc0;
            const int kb = kq * 32;
            const float* hp = hlds[parC];
            #pragma unroll 8
            for (int kk = 0; kk < 32; ++kk) {
                const int k = kb + kk;
                float4 w  = wlds4[k * 17 + ul + kq];
                float4 hv = *(const float4*)&hp[k * 16 + q0 * 4];
                acc0.x = fmaf(w.x, hv.x, acc0.x); acc0.y = fmaf(w.y, hv.x, acc0.y);
                acc0.z = fmaf(w.z, hv.x, acc0.z); acc0.w = fmaf(w.w, hv.x, acc0.w);
                acc1.x = fmaf(w.x, hv.y, acc1.x); acc1.y = fmaf(w.y, hv.y, acc1.y);
                acc1.z = fmaf(w.z, hv.y, acc1.z); acc1.w = fmaf(w.w, hv.y, acc1.w);
                acc2.x = fmaf(w.x, hv.z, acc2.x); acc2.y = fmaf(w.y, hv.z, acc2.y);
                acc2.z = fmaf(w.z, hv.z, acc2.z); acc2.w = fmaf(w.w, hv.z, acc2.w);
                acc3.x = fmaf(w.x, hv.w, acc3.x); acc3.y = fmaf(w.y, hv.w, acc3.y);
                acc3.z = fmaf(w.z, hv.w, acc3.z); acc3.w = fmaf(w.w, hv.w, acc3.w);
            }
            const float* xsrc = xst[parC];
            for (int jj = 0; jj < jcnt; ++jj) {
                const int j = joff + jj;
                float4 w  = xlds4[j * 17 + ul];
                float4 xv = *(const float4*)&xsrc[j * 20 + bq * 4];
                acc0.x = fmaf(w.x, xv.x, acc0.x); acc0.y = fmaf(w.y, xv.x, acc0.y);
                acc0.z = fmaf(w.z, xv.x, acc0.z); acc0.w = fmaf(w.w, xv.x, acc0.w);
                acc1.x = fmaf(w.x, xv.y, acc1.x); acc1.y = fmaf(w.y, xv.y, acc1.y);
                acc1.z = fmaf(w.z, xv.y, acc1.z); acc1.w = fmaf(w.w, xv.y, acc1.w);
                acc2.x = fmaf(w.x, xv.z, acc2.x); acc2.y = fmaf(w.y, xv.z, acc2.y);
                acc2.z = fmaf(w.z, xv.z, acc2.z); acc2.w = fmaf(w.w, xv.z, acc2.w);
                acc3.x = fmaf(w.x, xv.w, acc3.x); acc3.y = fmaf(w.y, xv.w, acc3.y);
                acc3.z = fmaf(w.z, xv.w, acc3.z); acc3.w = fmaf(w.w, xv.w, acc3.w);
            }
            const int rb = (kq * 16 + ul) * 17 + bq * 4;
            p4[rb + 0] = acc0; p4[rb + 1] = acc1;
            p4[rb + 2] = acc2; p4[rb + 3] = acc3;
        }
        __syncthreads();  // sync3

        // ================= E: finalize + stores ============================
        if (s <= 1022 && tid < 256) {
            const int fu = tid >> 4, fb = tid & 15;
            float4 gv = bg[fu];
            #pragma unroll
            for (int k2 = 0; k2 < 8; ++k2) {
                float4 p = p4[(k2 * 16 + fu) * 17 + fb];
                gv.x += p.x; gv.y += p.y; gv.z += p.z; gv.w += p.w;
            }
            float iv = sigf(gv.x), fv = sigf(gv.y);
            float gg = tanhf(gv.z), ov = sigf(gv.w);
            c_reg = fv * c_reg + iv * gg;
            float hval = ov * tanhf(c_reg);
            __hip_atomic_store(hbuf + parN * 65536 + (u0 + fu) * 256 + b0 + fb,
                               hval, __ATOMIC_RELAXED, __HIP_MEMORY_SCOPE_AGENT);
        }
        if (s >= 2 && s <= 1024 && tid >= 256 && tid < 356) {  // hid1 combine
            const int c = tid - 256;
            hid1L[parC][c] = fmaxf(ph1[0][c] + ph1[1][c] + b1[c], 0.f);
        }
        if (s >= 5 && tid >= 356 && tid < 436) {               // coeff/var flush
            const int t = s - 5;
            if ((t & 7) == 7 || t == 1022) {
                const int n = (t & 7) + 1, t0 = t - n + 1, fo = tid - 356;
                if (fo < 5 * n) {
                    out[(size_t)bhead * 5115 + t0 * 5 + fo] =
                        cvbuf[((t0 + fo / 5) & 7) * 10 + (fo % 5)];
                } else if (fo >= 40 && fo < 40 + 5 * n) {
                    const int f2 = fo - 40;
                    out[VARBASE + (size_t)bhead * 5115 + t0 * 5 + f2] =
                        cvbuf[((t0 + f2 / 5) & 7) * 10 + 5 + (f2 % 5)];
                }
            }
        }
        if (dopf) {
            xst[parN][pj0 * 20 + pb0] = xpf0;
            xst[parN][pj1 * 20 + pb1] = xpf1;
        }
        __syncthreads();  // sync4: drains vmcnt -> h stores complete
        if (s <= 1022 && tid == 0)
            __hip_atomic_store(&flags[g * 16 + ut], (unsigned)(s + 1),
                               __ATOMIC_RELAXED, __HIP_MEMORY_SCOPE_AGENT);
    }
}

extern "C" void kernel_launch(void* const* d_in, const int* in_sizes, int n_in,
                              void* d_out, int out_size, void* d_ws, size_t ws_size,
                              hipStream_t stream)
{
    const float* x    = (const float*)d_in[0];
    const float* W_ih = (const float*)d_in[1];
    const float* W_hh = (const float*)d_in[2];
    const float* b_ih = (const float*)d_in[3];
    const float* b_hh = (const float*)d_in[4];
    const float* W1   = (const float*)d_in[5];
    const float* b1   = (const float*)d_in[6];
    const float* W2   = (const float*)d_in[7];
    const float* b2   = (const float*)d_in[8];
    const float* W3   = (const float*)d_in[9];
    const float* b3   = (const float*)d_in[10];
    float* out = (float*)d_out;
    float* ws  = (float*)d_ws;

    hipMemsetAsync(ws + OFF_H,   0, 65536 * sizeof(float), stream);   // h_0 = 0
    hipMemsetAsync(ws + OFF_FLG, 0, 256 * sizeof(unsigned), stream);  // flags
    prep_pack<<<545, 256, 0, stream>>>(W_ih, W_hh, b_ih, b_hh, W1, W2, W3, ws);
    mdn_rnn_persist<<<256, 512, 0, stream>>>(x, b1, b2, b3, ws, out);
}

// Round 7
// 6007.058 us; speedup vs baseline: 2.2238x; 2.2238x over previous
//
#include <hip/hip_runtime.h>
#include <math.h>

// ---------------------------------------------------------------------------
// MDN-RNN round 7: MFMA LSTM (bf16 hi/lo, weights in registers), persistent
// kernel, cluster publish/poll, wave-aligned head roles.
//
// grid 256 WGs x 512 thr.  WG (ut=wg>>4, g=wg&15): units u0..+15, batches
// b0..+15, head batch bhead=b0+ut.  Cluster = 16 WGs sharing g (same XCD).
//
// LSTM per step: gates[64 rows=4g x 16u][16b] = Whh@h + Wih@x + bias via
// mfma_f32_16x16x32_bf16.  A-frags (Whh/Wih hi+lo) live in REGISTERS for all
// 1023 steps.  h exchanged as u32 = (lo16,hi16) bf16 pair (hi+lo ~ 16-bit
// mantissa).  Waves 0-3: gate w, Whi x (h_hi, h_lo).  Waves 4-7: gate w-4,
// Wlo x h_hi + x-passes.  C frags summed in E (pointwise, c in regs).
//
// Phases: A (L2/L3/FIN/poll, wave-aligned) | B stage h->frags | C MFMA + L1
// | E pointwise + h store + publish.  Lags: L1@s: h_s, L2: h_{s-1},
// L3: h_{s-2}, FIN: h_{s-3} -> t=s-4.  Loop s=0..1026.
// ---------------------------------------------------------------------------

#define NOUT 1023
#define KK   5
#define MEANBASE (256 * NOUT * KK)
#define VARBASE  (MEANBASE + 256 * NOUT * KK * 32)

// ws layout
#define OFF_HB   0            // u32[2][256][256] h ping-pong (hi,lo bf16 packed)
#define OFF_FLG  131072       // 256 uint flags (float index)
#define OFF_W1T  131136       // fp32 [256k][128ch]
#define OFF_W2T  163904       // fp32 [100k][128ch]
#define OFF_W3T  176704       // fp32 [100k][192ch]

typedef __attribute__((ext_vector_type(8))) short s8t;
typedef __attribute__((ext_vector_type(4))) float f4t;

__device__ __forceinline__ float sigf(float x) { return 1.0f / (1.0f + expf(-x)); }
__device__ __forceinline__ unsigned short f2bf(float f) {
    unsigned u = __float_as_uint(f);
    u += 0x7fffu + ((u >> 16) & 1u);
    return (unsigned short)(u >> 16);
}
__device__ __forceinline__ float bf2f(unsigned short h) {
    return __uint_as_float(((unsigned)h) << 16);
}

// ------------------- one-time: transposed head weights ----------------------
__global__ __launch_bounds__(256) void prep_pack(
    const float* __restrict__ W1, const float* __restrict__ W2,
    const float* __restrict__ W3, float* __restrict__ ws)
{
    const int idx = blockIdx.x * 256 + threadIdx.x;
    if (idx < 32768) {                       // W1T[k 256][128]
        int k = idx >> 7, c = idx & 127;
        if (c < 100) ws[OFF_W1T + idx] = W1[c * 256 + k];
    } else if (idx < 45568) {                // W2T[k 100][128]
        int r = idx - 32768;
        int k = r >> 7, c = r & 127;
        if (c < 100) ws[OFF_W2T + r] = W2[c * 100 + k];
    } else if (idx < 64768) {                // W3T[k 100][192]
        int r = idx - 45568;
        int k = r / 192, c = r - k * 192;
        if (c < 170) ws[OFF_W3T + r] = W3[c * 100 + k];
    }
}

// ------------------------------ persistent kernel ---------------------------
__global__ __launch_bounds__(512, 1) void mdn_rnn_persist(
    const float* __restrict__ x,
    const float* __restrict__ W_ih, const float* __restrict__ W_hh,
    const float* __restrict__ b_ih, const float* __restrict__ b_hh,
    const float* __restrict__ b1, const float* __restrict__ b2,
    const float* __restrict__ b3,
    float* __restrict__ ws, float* __restrict__ out)
{
    __shared__ unsigned short hHi[4096], hLo[4096];  // [sk8][kg4][n16][j8]
    __shared__ unsigned short xHi[1024], xLo[1024];  // [sk2][kg4][n16][j8]
    __shared__ float hcolL[256];                     // fp32 h column (n==ut)
    __shared__ float gC[8 * 256];                    // C frags [w][lane][4]
    __shared__ float ph1[4][104];
    __shared__ float hid1L[2][104], hid2L[2][104], oL[2][176];
    __shared__ f4t   bgv[16];
    __shared__ float xst[2][704];                    // [j35][b16 pad20]

    const int tid  = threadIdx.x;
    const int wg   = blockIdx.x;
    const int ut   = wg >> 4;
    const int g    = wg & 15;
    const int u0   = ut * 16;
    const int b0   = g * 16;
    const int bhead = b0 + ut;
    const int wave = tid >> 6;
    const int lane = tid & 63;

    unsigned* hb = (unsigned*)ws;                    // OFF_HB
    unsigned* flags = (unsigned*)(ws + OFF_FLG);

    // x prefetch mapping (tid < 280, 2 elems each of 16b x 35j)
    const int e0 = tid * 2, pb0 = e0 / 35, pj0 = e0 - pb0 * 35;
    const int e1 = e0 + 1,  pb1 = e1 / 35, pj1 = e1 - pb1 * 35;

    // ---- A-fragment init (registers, persistent all steps) ----
    s8t aW[8];            // waves 0-3: Whh_hi, waves 4-7: Whh_lo
    s8t aXh[2], aXl[2];   // waves 4-7 only: Wih hi/lo (zero-padded k>=35)
    {
        const int gg = wave & 3;
        const int ui = lane & 15, kb8 = (lane >> 4) * 8;
        #pragma unroll
        for (int sk = 0; sk < 8; ++sk) {
            s8t v;
            #pragma unroll
            for (int j = 0; j < 8; ++j) {
                float wv = W_hh[(size_t)(gg * 256 + u0 + ui) * 256 + sk * 32 + kb8 + j];
                unsigned short hi = f2bf(wv);
                v[j] = (wave < 4) ? (short)hi : (short)f2bf(wv - bf2f(hi));
            }
            aW[sk] = v;
        }
        if (wave >= 4) {
            #pragma unroll
            for (int sk = 0; sk < 2; ++sk) {
                s8t vh, vl;
                #pragma unroll
                for (int j = 0; j < 8; ++j) {
                    int k = sk * 32 + kb8 + j;
                    float wv = (k < 35) ?
                        W_ih[(size_t)(gg * 256 + u0 + ui) * 35 + k] : 0.f;
                    unsigned short hi = f2bf(wv);
                    vh[j] = (short)hi;
                    vl[j] = (short)f2bf(wv - bf2f(hi));
                }
                aXh[sk] = vh; aXl[sk] = vl;
            }
        } else {
            aXh[0] = aXh[1] = aXl[0] = aXl[1] = (s8t)0;
        }
    }
    if (tid < 16)
        bgv[tid] = (f4t){ b_ih[u0 + tid]       + b_hh[u0 + tid],
                          b_ih[256 + u0 + tid] + b_hh[256 + u0 + tid],
                          b_ih[512 + u0 + tid] + b_hh[512 + u0 + tid],
                          b_ih[768 + u0 + tid] + b_hh[768 + u0 + tid] };
    if (tid < 280) {
        xst[0][pj0 * 20 + pb0] = x[(size_t)(b0 + pb0) * 35840 + pj0];
        xst[0][pj1 * 20 + pb1] = x[(size_t)(b0 + pb1) * 35840 + pj1];
    }
    __syncthreads();

    float c_reg = 0.0f;

    for (int s = 0; s < 1027; ++s) {
        const int parC = s & 1;
        const int parN = parC ^ 1;

        // ============ A: head roles + poll (all wave-aligned) ==============
        float xpf0 = 0.f, xpf1 = 0.f;
        const bool dopf = (s < 1022) && (tid < 280);
        if (dopf) {
            const float* xp = x + (size_t)(s + 1) * 35;
            xpf0 = __builtin_nontemporal_load(xp + (size_t)(b0 + pb0) * 35840 + pj0);
            xpf1 = __builtin_nontemporal_load(xp + (size_t)(b0 + pb1) * 35840 + pj1);
        }
        if (tid < 100) {                                   // L2
            if (s >= 2 && s <= 1024) {
                const float* W2T = ws + OFF_W2T;
                float a0 = 0.f, a1 = 0.f;
                #pragma unroll 10
                for (int k = 0; k < 50; ++k) {
                    a0 = fmaf(W2T[k * 128 + tid],        hid1L[parN][k],      a0);
                    a1 = fmaf(W2T[(k + 50) * 128 + tid], hid1L[parN][k + 50], a1);
                }
                hid2L[parC][tid] = fmaxf(a0 + a1 + b2[tid], 0.f);
            }
        } else if (tid >= 128 && tid < 298) {              // L3
            if (s >= 3 && s <= 1025) {
                const int ch = tid - 128;
                const float* W3T = ws + OFF_W3T;
                float a0 = 0.f, a1 = 0.f;
                #pragma unroll 10
                for (int k = 0; k < 50; ++k) {
                    a0 = fmaf(W3T[k * 192 + ch],        hid2L[parN][k],      a0);
                    a1 = fmaf(W3T[(k + 50) * 192 + ch], hid2L[parN][k + 50], a1);
                }
                oL[parC][ch] = a0 + a1 + b3[ch];
            }
        } else if (tid >= 320 && tid < 490) {              // FIN: t = s-4
            if (s >= 4) {
                const int ch = tid - 320;
                const int t  = s - 4;
                float m5 = oL[parN][0];
                #pragma unroll
                for (int k = 1; k < KK; ++k) m5 = fmaxf(m5, oL[parN][k]);
                float den = 0.f;
                #pragma unroll
                for (int k = 0; k < KK; ++k) den += expf(oL[parN][k] - m5);
                float v = oL[parN][ch];
                if (ch < KK)
                    out[(size_t)bhead * 5115 + (size_t)t * 5 + ch] = expf(v - m5) / den;
                else if (ch < 2 * KK)
                    out[VARBASE + (size_t)bhead * 5115 + (size_t)t * 5 + (ch - 5)] = expf(v);
                else
                    out[MEANBASE + ((size_t)bhead * NOUT + t) * 160 + (ch - 10)] = v;
            }
        } else if (tid >= 490 && tid < 506) {              // poll cluster flags
            if (s >= 1 && s <= 1023) {
                const unsigned tgt = (unsigned)s;
                while (__hip_atomic_load(&flags[g * 16 + (tid - 490)],
                                         __ATOMIC_RELAXED,
                                         __HIP_MEMORY_SCOPE_AGENT) < tgt)
                    __builtin_amdgcn_s_sleep(1);
            }
        }
        __syncthreads();  // syncA

        // ============ B: stage h_s -> bf16 frag LDS (+x frags) =============
        if (s <= 1023) {
            const int sk = tid >> 6, kg = (tid >> 4) & 3, n = tid & 15;
            const unsigned* src = hb + parC * 65536 + (sk * 32 + kg * 8) * 256 + b0 + n;
            unsigned v[8];
            #pragma unroll
            for (int j = 0; j < 8; ++j)
                v[j] = __hip_atomic_load(src + j * 256, __ATOMIC_RELAXED,
                                         __HIP_MEMORY_SCOPE_AGENT);
            s8t h8, l8;
            float fc[8];
            #pragma unroll
            for (int j = 0; j < 8; ++j) {
                unsigned short hi = (unsigned short)(v[j] & 0xffffu);
                unsigned short lo = (unsigned short)(v[j] >> 16);
                h8[j] = (short)hi; l8[j] = (short)lo;
                fc[j] = bf2f(hi) + bf2f(lo);
            }
            *(s8t*)&hHi[sk * 512 + kg * 128 + n * 8] = h8;
            *(s8t*)&hLo[sk * 512 + kg * 128 + n * 8] = l8;
            if (n == ut) {
                #pragma unroll
                for (int j = 0; j < 8; ++j) hcolL[sk * 32 + kg * 8 + j] = fc[j];
            }
            if (tid < 128) {                               // x frags
                const int sk2 = tid >> 6;
                s8t xh8, xl8;
                #pragma unroll
                for (int j = 0; j < 8; ++j) {
                    int k = sk2 * 32 + kg * 8 + j;
                    float xv = (k < 35) ? xst[parC][k * 20 + n] : 0.f;
                    unsigned short hi = f2bf(xv);
                    xh8[j] = (short)hi;
                    xl8[j] = (short)f2bf(xv - bf2f(hi));
                }
                *(s8t*)&xHi[sk2 * 512 + kg * 128 + n * 8] = xh8;
                *(s8t*)&xLo[sk2 * 512 + kg * 128 + n * 8] = xl8;
            }
        }
        __syncthreads();  // syncB

        // ============ C: MFMA gates + L1 (VALU) ============================
        if (s <= 1022) {
            f4t acc = (f4t){0.f, 0.f, 0.f, 0.f};
            const int fo = lane * 8;
            if (wave < 4) {
                #pragma unroll
                for (int sk = 0; sk < 8; ++sk) {
                    s8t bh = *(const s8t*)&hHi[sk * 512 + fo];
                    acc = __builtin_amdgcn_mfma_f32_16x16x32_bf16(aW[sk], bh, acc, 0, 0, 0);
                }
                #pragma unroll
                for (int sk = 0; sk < 8; ++sk) {
                    s8t bl = *(const s8t*)&hLo[sk * 512 + fo];
                    acc = __builtin_amdgcn_mfma_f32_16x16x32_bf16(aW[sk], bl, acc, 0, 0, 0);
                }
            } else {
                #pragma unroll
                for (int sk = 0; sk < 8; ++sk) {
                    s8t bh = *(const s8t*)&hHi[sk * 512 + fo];
                    acc = __builtin_amdgcn_mfma_f32_16x16x32_bf16(aW[sk], bh, acc, 0, 0, 0);
                }
                #pragma unroll
                for (int sk = 0; sk < 2; ++sk) {
                    s8t xh = *(const s8t*)&xHi[sk * 512 + fo];
                    s8t xl = *(const s8t*)&xLo[sk * 512 + fo];
                    acc = __builtin_amdgcn_mfma_f32_16x16x32_bf16(aXh[sk], xh, acc, 0, 0, 0);
                    acc = __builtin_amdgcn_mfma_f32_16x16x32_bf16(aXh[sk], xl, acc, 0, 0, 0);
                    acc = __builtin_amdgcn_mfma_f32_16x16x32_bf16(aXl[sk], xh, acc, 0, 0, 0);
                }
            }
            *(f4t*)&gC[(wave * 64 + lane) * 4] = acc;
        }
        {
            const int kq = tid >> 7, ch = tid & 127;
            if (s >= 1 && s <= 1023 && ch < 100) {         // L1: hid1(h_s)
                const float* W1p = ws + OFF_W1T + kq * 64 * 128 + ch;
                float a0 = 0.f;
                #pragma unroll 4
                for (int kk = 0; kk < 64; kk += 4) {
                    f4t hv = *(const f4t*)&hcolL[kq * 64 + kk];
                    a0 = fmaf(W1p[(kk + 0) * 128], hv.x, a0);
                    a0 = fmaf(W1p[(kk + 1) * 128], hv.y, a0);
                    a0 = fmaf(W1p[(kk + 2) * 128], hv.z, a0);
                    a0 = fmaf(W1p[(kk + 3) * 128], hv.w, a0);
                }
                ph1[kq][ch] = a0;
            }
        }
        __syncthreads();  // syncC

        // ============ E: pointwise + stores + publish ======================
        if (s <= 1022 && tid < 256) {
            const int fu = tid >> 4, fb = tid & 15;
            const int base = (((fu >> 2) * 16 + fb) * 4) + (fu & 3);
            f4t bb = bgv[fu];
            float gi  = gC[base]       + gC[4 * 256 + base] + bb.x;
            float gf  = gC[256 + base] + gC[5 * 256 + base] + bb.y;
            float gg_ = gC[512 + base] + gC[6 * 256 + base] + bb.z;
            float go  = gC[768 + base] + gC[7 * 256 + base] + bb.w;
            float iv = sigf(gi), fv = sigf(gf);
            float gv = tanhf(gg_), ov = sigf(go);
            c_reg = fv * c_reg + iv * gv;
            float hval = ov * tanhf(c_reg);
            unsigned short hi = f2bf(hval);
            unsigned short lo = f2bf(hval - bf2f(hi));
            unsigned pk = ((unsigned)lo << 16) | (unsigned)hi;
            __hip_atomic_store(hb + parN * 65536 + (u0 + fu) * 256 + (b0 + fb),
                               pk, __ATOMIC_RELAXED, __HIP_MEMORY_SCOPE_AGENT);
        }
        if (s >= 1 && s <= 1023 && tid >= 256 && tid < 356) {   // hid1 combine
            const int c = tid - 256;
            hid1L[parC][c] =
                fmaxf(ph1[0][c] + ph1[1][c] + ph1[2][c] + ph1[3][c] + b1[c], 0.f);
        }
        if (dopf) {
            xst[parN][pj0 * 20 + pb0] = xpf0;
            xst[parN][pj1 * 20 + pb1] = xpf1;
        }
        __syncthreads();  // syncE: drains vmcnt -> h stores complete
        if (s <= 1022 && tid == 0)
            __hip_atomic_store(&flags[g * 16 + ut], (unsigned)(s + 1),
                               __ATOMIC_RELAXED, __HIP_MEMORY_SCOPE_AGENT);
    }
}

extern "C" void kernel_launch(void* const* d_in, const int* in_sizes, int n_in,
                              void* d_out, int out_size, void* d_ws, size_t ws_size,
                              hipStream_t stream)
{
    const float* x    = (const float*)d_in[0];
    const float* W_ih = (const float*)d_in[1];
    const float* W_hh = (const float*)d_in[2];
    const float* b_ih = (const float*)d_in[3];
    const float* b_hh = (const float*)d_in[4];
    const float* W1   = (const float*)d_in[5];
    const float* b1   = (const float*)d_in[6];
    const float* W2   = (const float*)d_in[7];
    const float* b2   = (const float*)d_in[8];
    const float* W3   = (const float*)d_in[9];
    const float* b3   = (const float*)d_in[10];
    float* out = (float*)d_out;
    float* ws  = (float*)d_ws;

    hipMemsetAsync(ws, 0, 65536 * sizeof(unsigned), stream);            // h_0 = 0
    hipMemsetAsync(ws + OFF_FLG, 0, 256 * sizeof(unsigned), stream);    // flags
    prep_pack<<<254, 256, 0, stream>>>(W1, W2, W3, ws);
    mdn_rnn_persist<<<256, 512, 0, stream>>>(x, W_ih, W_hh, b_ih, b_hh,
                                             b1, b2, b3, ws, out);
}